// Round 2
// baseline (1170.148 us; speedup 1.0000x reference)
//
#include <hip/hip_runtime.h>
#include <cstddef>
#include <cstdint>

typedef __attribute__((ext_vector_type(8))) short bf16x8;
typedef __attribute__((ext_vector_type(4))) float f32x4;
typedef unsigned short ushort_t;

__device__ inline short f2bf(float f) {
  union { float f; unsigned u; } c; c.f = f;
  unsigned u = c.u;
  return (short)((u + 0x7FFFu + ((u >> 16) & 1u)) >> 16);
}
__device__ inline float ubits(unsigned u) { union { unsigned u; float f; } c; c.u = u; return c.f; }
__device__ inline float bf2f(ushort_t u) { return ubits(((unsigned)u) << 16); }
__device__ inline float fsig(float x) { return __builtin_amdgcn_rcpf(1.f + __expf(-x)); }
__device__ inline float ftanh(float x) {
  float t = __expf(-2.f * fabsf(x));
  return copysignf((1.f - t) * __builtin_amdgcn_rcpf(1.f + t), x);
}

// bf16 weight mats, row-major [128][128]:
// 0: Wzf (W_z_w[:, :128])  1: Wzh (W_z_w[:, 128:])  2: Wr (W_r_w)
// 3: Whf (W_h_w[:, :128])  4: Whh (W_h_w[:, 128:])  5: Ur (U_r_w)
__global__ __launch_bounds__(256) void conv_weights(
    const float* __restrict__ Wz, const float* __restrict__ Wr,
    const float* __restrict__ Ur, const float* __restrict__ Wh,
    short* __restrict__ out)
{
  int i = blockIdx.x * 256 + threadIdx.x;
  if (i >= 6 * 16384) return;
  int mat = i >> 14, idx = i & 16383;
  int o = idx >> 7, c = idx & 127;
  float v = 0.f;
  switch (mat) {
    case 0: v = Wz[o * 256 + c];        break;
    case 1: v = Wz[o * 256 + 128 + c];  break;
    case 2: v = Wr[o * 128 + c];        break;
    case 3: v = Wh[o * 256 + c];        break;
    case 4: v = Wh[o * 256 + 128 + c];  break;
    case 5: v = Ur[o * 128 + c];        break;
  }
  out[i] = f2bf(v);
}

// Detect whether bgraph arrived as int64 (odd 32-bit words all zero).
__global__ void detect64(const int* __restrict__ bg, int* __restrict__ flag) {
  int t = threadIdx.x;
  int v = bg[2 * t + 1];
  unsigned long long m = __ballot(v == 0);
  if (t == 0) *flag = (m == ~0ull) ? 1 : 0;
}

// MODE: 0 = first step (h=0: no gather), 1 = middle (bf16 h out), 2 = last (fp32 out)
// INLP: fuse P_next = h_next @ Ur^T into the epilogue.
template<int MODE, bool INLP>
__global__ __launch_bounds__(256, 3) void step_k(
    const float* __restrict__ fmess,
    const int* __restrict__ bg,
    const int* __restrict__ flag64,
    const ushort_t* __restrict__ hin,
    const ushort_t* __restrict__ Pin,
    const short* __restrict__ wbf,
    const float* __restrict__ bz, const float* __restrict__ urb, const float* __restrict__ bh,
    ushort_t* __restrict__ houtb, float* __restrict__ houtf,
    ushort_t* __restrict__ Pout, int E)
{
  __shared__ __align__(16) short s_fm[32][136];
  __shared__ __align__(16) short s_R1[32][136];
  __shared__ __align__(16) short s_sb[32][136];
  __shared__ __align__(16) short s_gb[32][136];
  __shared__ __align__(16) float s_sum[32][132];

  const int tid = threadIdx.x, wave = tid >> 6, lane = tid & 63;
  const int cl = lane & 15, kg = lane >> 4;
  const int base = blockIdx.x * 32;
  const int mrow = (wave & 1) * 16, ncol = (wave >> 1) * 64;

  // ---- phase 1: fmess tile -> LDS (bf16) ----
  #pragma unroll
  for (int it = 0; it < 4; ++it) {
    int idx = it * 256 + tid;            // 1024 float4 slots = 32x128
    int r = idx >> 5, c = (idx & 31) << 2;
    float4 v = {0.f, 0.f, 0.f, 0.f};
    int e = base + r;
    if (e < E) v = *reinterpret_cast<const float4*>(fmess + (size_t)e * 128 + c);
    s_fm[r][c]     = f2bf(v.x);
    s_fm[r][c + 1] = f2bf(v.y);
    s_fm[r][c + 2] = f2bf(v.z);
    s_fm[r][c + 3] = f2bf(v.w);
  }
  __syncthreads();

  // ---- phase 2: fmess projections (Zf, Hf kept in regs; R1 -> LDS) ----
  bf16x8 af[4];
  #pragma unroll
  for (int ks = 0; ks < 4; ++ks)
    af[ks] = *reinterpret_cast<const bf16x8*>(&s_fm[mrow + cl][ks * 32 + kg * 8]);

  const short* Wzf = wbf;
  const short* Wzh = wbf + 1 * 16384;
  const short* Wr  = wbf + 2 * 16384;
  const short* Whf = wbf + 3 * 16384;
  const short* Whh = wbf + 4 * 16384;
  const short* Ur  = wbf + 5 * 16384;

  f32x4 zacc[4], hacc[4];
  #pragma unroll
  for (int nt = 0; nt < 4; ++nt) { zacc[nt] = (f32x4){0,0,0,0}; hacc[nt] = (f32x4){0,0,0,0}; }
  #pragma unroll
  for (int ks = 0; ks < 4; ++ks) {
    #pragma unroll
    for (int nt = 0; nt < 4; ++nt) {
      int n = ncol + nt * 16 + cl;
      bf16x8 b1 = *reinterpret_cast<const bf16x8*>(Wzf + (size_t)n * 128 + ks * 32 + kg * 8);
      zacc[nt] = __builtin_amdgcn_mfma_f32_16x16x32_bf16(af[ks], b1, zacc[nt], 0, 0, 0);
      bf16x8 b2 = *reinterpret_cast<const bf16x8*>(Whf + (size_t)n * 128 + ks * 32 + kg * 8);
      hacc[nt] = __builtin_amdgcn_mfma_f32_16x16x32_bf16(af[ks], b2, hacc[nt], 0, 0, 0);
    }
  }

  f32x4 accz[4], acch[4];
  #pragma unroll
  for (int nt = 0; nt < 4; ++nt) { accz[nt] = (f32x4){0,0,0,0}; acch[nt] = (f32x4){0,0,0,0}; }

  if (MODE != 0) {
    // R1 = fmess @ Wr^T + urb  -> LDS (bf16)
    {
      f32x4 racc[4];
      #pragma unroll
      for (int nt = 0; nt < 4; ++nt) racc[nt] = (f32x4){0,0,0,0};
      #pragma unroll
      for (int ks = 0; ks < 4; ++ks) {
        #pragma unroll
        for (int nt = 0; nt < 4; ++nt) {
          bf16x8 b = *reinterpret_cast<const bf16x8*>(Wr + (size_t)(ncol + nt * 16 + cl) * 128 + ks * 32 + kg * 8);
          racc[nt] = __builtin_amdgcn_mfma_f32_16x16x32_bf16(af[ks], b, racc[nt], 0, 0, 0);
        }
      }
      #pragma unroll
      for (int nt = 0; nt < 4; ++nt) {
        int n = ncol + nt * 16 + cl;
        float bias = urb[n];
        #pragma unroll
        for (int r = 0; r < 4; ++r)
          s_R1[mrow + kg * 4 + r][n] = f2bf(racc[nt][r] + bias);
      }
    }
    __syncthreads();

    // ---- phase 3: gather h/P rows (bf16), sum + gated sum ----
    const int f64 = *flag64;
    const int c0 = lane * 2;
    for (int rr = 0; rr < 8; ++rr) {
      int row = wave * 8 + rr;
      int e = base + row;
      float sh0 = 0.f, sh1 = 0.f, g0 = 0.f, g1 = 0.f;
      if (e < E) {
        float r1x = bf2f((ushort_t)s_R1[row][c0]);
        float r1y = bf2f((ushort_t)s_R1[row][c0 + 1]);
        size_t eb = (size_t)e * 8;
        int my = 0;
        if (lane < 8) my = f64 ? bg[(eb + lane) * 2] : bg[eb + lane];
        #pragma unroll
        for (int k = 0; k < 8; ++k) {
          int idx = __shfl(my, k);
          unsigned hb = *reinterpret_cast<const unsigned*>(hin + (size_t)idx * 128 + c0);
          unsigned pb = *reinterpret_cast<const unsigned*>(Pin + (size_t)idx * 128 + c0);
          float hx = ubits(hb << 16), hy = ubits(hb & 0xffff0000u);
          float px = ubits(pb << 16), py = ubits(pb & 0xffff0000u);
          sh0 += hx; sh1 += hy;
          g0 += fsig(r1x + px) * hx;
          g1 += fsig(r1y + py) * hy;
        }
      }
      s_sum[row][c0] = sh0; s_sum[row][c0 + 1] = sh1;
      unsigned sp = ((unsigned)(ushort_t)f2bf(sh1) << 16) | (ushort_t)(unsigned short)f2bf(sh0);
      unsigned gp = ((unsigned)(ushort_t)f2bf(g1) << 16) | (ushort_t)(unsigned short)f2bf(g0);
      *reinterpret_cast<unsigned*>(&s_sb[row][c0]) = sp;
      *reinterpret_cast<unsigned*>(&s_gb[row][c0]) = gp;
    }
    __syncthreads();

    // ---- phase 4: z/h hidden-state GEMMs ----
    bf16x8 az[4], ag[4];
    #pragma unroll
    for (int ks = 0; ks < 4; ++ks) {
      az[ks] = *reinterpret_cast<const bf16x8*>(&s_sb[mrow + cl][ks * 32 + kg * 8]);
      ag[ks] = *reinterpret_cast<const bf16x8*>(&s_gb[mrow + cl][ks * 32 + kg * 8]);
    }
    #pragma unroll
    for (int ks = 0; ks < 4; ++ks) {
      #pragma unroll
      for (int nt = 0; nt < 4; ++nt) {
        int n = ncol + nt * 16 + cl;
        bf16x8 b1 = *reinterpret_cast<const bf16x8*>(Wzh + (size_t)n * 128 + ks * 32 + kg * 8);
        accz[nt] = __builtin_amdgcn_mfma_f32_16x16x32_bf16(az[ks], b1, accz[nt], 0, 0, 0);
        bf16x8 b2 = *reinterpret_cast<const bf16x8*>(Whh + (size_t)n * 128 + ks * 32 + kg * 8);
        acch[nt] = __builtin_amdgcn_mfma_f32_16x16x32_bf16(ag[ks], b2, acch[nt], 0, 0, 0);
      }
    }
    if (INLP) __syncthreads();   // frag reads of s_sb done before epilogue overwrites it
  }

  // ---- phase 5: GRU epilogue ----
  #pragma unroll
  for (int nt = 0; nt < 4; ++nt) {
    int n = ncol + nt * 16 + cl;
    float bzv = bz[n], bhv = bh[n];
    #pragma unroll
    for (int r = 0; r < 4; ++r) {
      int rowt = mrow + kg * 4 + r;
      int e = base + rowt;
      float z   = fsig(zacc[nt][r] + accz[nt][r] + bzv);
      float pre = ftanh(hacc[nt][r] + acch[nt][r] + bhv);
      float sh  = (MODE == 0) ? 0.f : s_sum[rowt][n];
      float nh  = (1.f - z) * sh + z * pre;
      if (e == 0) nh = 0.f;
      if (e < E) {
        if (MODE == 2) houtf[(size_t)e * 128 + n] = nh;
        else           houtb[(size_t)e * 128 + n] = (ushort_t)f2bf(nh);
      }
      if (INLP) s_sb[rowt][n] = f2bf(nh);
    }
  }

  // ---- phase 6 (optional): P_next = h_next @ Ur^T ----
  if (INLP) {
    __syncthreads();
    bf16x8 ah[4];
    #pragma unroll
    for (int ks = 0; ks < 4; ++ks)
      ah[ks] = *reinterpret_cast<const bf16x8*>(&s_sb[mrow + cl][ks * 32 + kg * 8]);
    f32x4 pacc[4];
    #pragma unroll
    for (int nt = 0; nt < 4; ++nt) pacc[nt] = (f32x4){0,0,0,0};
    #pragma unroll
    for (int ks = 0; ks < 4; ++ks) {
      #pragma unroll
      for (int nt = 0; nt < 4; ++nt) {
        bf16x8 b = *reinterpret_cast<const bf16x8*>(Ur + (size_t)(ncol + nt * 16 + cl) * 128 + ks * 32 + kg * 8);
        pacc[nt] = __builtin_amdgcn_mfma_f32_16x16x32_bf16(ah[ks], b, pacc[nt], 0, 0, 0);
      }
    }
    #pragma unroll
    for (int nt = 0; nt < 4; ++nt) {
      int n = ncol + nt * 16 + cl;
      #pragma unroll
      for (int r = 0; r < 4; ++r) {
        int e = base + mrow + kg * 4 + r;
        if (e < E) Pout[(size_t)e * 128 + n] = (ushort_t)f2bf(pacc[nt][r]);
      }
    }
  }
}

// Plan-B standalone P GEMM: P = h(bf16) @ Ur^T
__global__ __launch_bounds__(256, 4) void gemmP(
    const ushort_t* __restrict__ A, const short* __restrict__ Ur,
    ushort_t* __restrict__ P, int E)
{
  const int tid = threadIdx.x, wave = tid >> 6, lane = tid & 63;
  const int cl = lane & 15, kg = lane >> 4;
  const int base = blockIdx.x * 64;
  int ar = base + wave * 16 + cl; if (ar >= E) ar = E - 1;
  bf16x8 af[4];
  #pragma unroll
  for (int ks = 0; ks < 4; ++ks)
    af[ks] = *reinterpret_cast<const bf16x8*>(A + (size_t)ar * 128 + ks * 32 + kg * 8);
  f32x4 acc[8];
  #pragma unroll
  for (int nt = 0; nt < 8; ++nt) acc[nt] = (f32x4){0,0,0,0};
  #pragma unroll
  for (int ks = 0; ks < 4; ++ks) {
    #pragma unroll
    for (int nt = 0; nt < 8; ++nt) {
      bf16x8 b = *reinterpret_cast<const bf16x8*>(Ur + (size_t)(nt * 16 + cl) * 128 + ks * 32 + kg * 8);
      acc[nt] = __builtin_amdgcn_mfma_f32_16x16x32_bf16(af[ks], b, acc[nt], 0, 0, 0);
    }
  }
  #pragma unroll
  for (int nt = 0; nt < 8; ++nt) {
    #pragma unroll
    for (int r = 0; r < 4; ++r) {
      int row = base + wave * 16 + kg * 4 + r;
      if (row < E) P[(size_t)row * 128 + nt * 16 + cl] = (ushort_t)f2bf(acc[nt][r]);
    }
  }
}

__global__ __launch_bounds__(256) void expand_bf(const ushort_t* __restrict__ src,
                                                 float* __restrict__ dst, size_t n)
{
  size_t i = ((size_t)blockIdx.x * 256 + threadIdx.x) * 4;
  if (i < n) {
    const ushort_t* s = src + i;
    float4 o = { bf2f(s[0]), bf2f(s[1]), bf2f(s[2]), bf2f(s[3]) };
    *reinterpret_cast<float4*>(dst + i) = o;
  }
}

extern "C" void kernel_launch(void* const* d_in, const int* in_sizes, int n_in,
                              void* d_out, int out_size, void* d_ws, size_t ws_size,
                              hipStream_t stream) {
  const float* fmess = (const float*)d_in[0];
  const int*   bg    = (const int*)d_in[1];
  const float* Wz    = (const float*)d_in[2];
  const float* bz    = (const float*)d_in[3];
  const float* Wrw   = (const float*)d_in[4];
  const float* Urw   = (const float*)d_in[5];
  const float* urb   = (const float*)d_in[6];
  const float* Wh    = (const float*)d_in[7];
  const float* bh    = (const float*)d_in[8];
  float* out = (float*)d_out;

  const int E = in_sizes[0] / 128;
  const size_t EH = (size_t)E * 128;

  ushort_t* D0 = (ushort_t*)d_out;   // d_out doubles as bf16 scratch until last step
  ushort_t* D1 = D0 + EH;

  const size_t wbytes = 6 * 16384 * sizeof(short) + 64;
  const int grid = (E + 31) / 32;

  if (ws_size >= 2 * EH * sizeof(ushort_t) + wbytes) {
    // ---- Plan A: {h,P} ping-pong between d_out pair and ws pair; P fused. ----
    ushort_t* Wa = (ushort_t*)d_ws;
    ushort_t* Wb = Wa + EH;
    short* wbf = (short*)(Wb + EH);
    int* flag = (int*)(wbf + 6 * 16384);
    conv_weights<<<384, 256, 0, stream>>>(Wz, Wrw, Urw, Wh, wbf);
    detect64<<<1, 64, 0, stream>>>(bg, flag);
    step_k<0, true><<<grid, 256, 0, stream>>>(fmess, bg, flag, nullptr, nullptr, wbf, bz, urb, bh, D0, nullptr, D1, E);
    step_k<1, true><<<grid, 256, 0, stream>>>(fmess, bg, flag, D0, D1, wbf, bz, urb, bh, Wa, nullptr, Wb, E);
    step_k<1, true><<<grid, 256, 0, stream>>>(fmess, bg, flag, Wa, Wb, wbf, bz, urb, bh, D0, nullptr, D1, E);
    step_k<1, true><<<grid, 256, 0, stream>>>(fmess, bg, flag, D0, D1, wbf, bz, urb, bh, Wa, nullptr, Wb, E);
    step_k<2, false><<<grid, 256, 0, stream>>>(fmess, bg, flag, Wa, Wb, wbf, bz, urb, bh, nullptr, out, nullptr, E);
  } else {
    // ---- Plan B: single ws buffer; separate P GEMM; bf16 final + expand. ----
    ushort_t* Wa = (ushort_t*)d_ws;
    short* wbf = (short*)(Wa + EH);
    int* flag = (int*)(wbf + 6 * 16384);
    conv_weights<<<384, 256, 0, stream>>>(Wz, Wrw, Urw, Wh, wbf);
    detect64<<<1, 64, 0, stream>>>(bg, flag);
    const int gp = (E + 63) / 64;
    step_k<0, false><<<grid, 256, 0, stream>>>(fmess, bg, flag, nullptr, nullptr, wbf, bz, urb, bh, D0, nullptr, nullptr, E);
    gemmP<<<gp, 256, 0, stream>>>(D0, wbf + 5 * 16384, Wa, E);
    step_k<1, false><<<grid, 256, 0, stream>>>(fmess, bg, flag, D0, Wa, wbf, bz, urb, bh, D1, nullptr, nullptr, E);
    gemmP<<<gp, 256, 0, stream>>>(D1, wbf + 5 * 16384, Wa, E);
    step_k<1, false><<<grid, 256, 0, stream>>>(fmess, bg, flag, D1, Wa, wbf, bz, urb, bh, D0, nullptr, nullptr, E);
    gemmP<<<gp, 256, 0, stream>>>(D0, wbf + 5 * 16384, Wa, E);
    step_k<1, false><<<grid, 256, 0, stream>>>(fmess, bg, flag, D0, Wa, wbf, bz, urb, bh, D1, nullptr, nullptr, E);
    gemmP<<<gp, 256, 0, stream>>>(D1, wbf + 5 * 16384, Wa, E);
    step_k<1, false><<<grid, 256, 0, stream>>>(fmess, bg, flag, D1, Wa, wbf, bz, urb, bh, D0, nullptr, nullptr, E);
    hipMemcpyAsync(Wa, D0, EH * sizeof(ushort_t), hipMemcpyDeviceToDevice, stream);
    expand_bf<<<(int)((EH / 4 + 255) / 256), 256, 0, stream>>>(Wa, out, EH);
  }
}

// Round 3
// 1115.069 us; speedup vs baseline: 1.0494x; 1.0494x over previous
//
#include <hip/hip_runtime.h>
#include <cstddef>
#include <cstdint>

typedef __attribute__((ext_vector_type(8))) short bf16x8;
typedef __attribute__((ext_vector_type(4))) float f32x4;
typedef unsigned int u32t;
typedef unsigned short u16t;

__device__ inline u16t f2bf(float f) {
  union { float f; unsigned u; } c; c.f = f;
  return (u16t)((c.u + 0x7FFFu + ((c.u >> 16) & 1u)) >> 16);
}
__device__ inline float ubits(u32t u) { union { u32t u; float f; } c; c.u = u; return c.f; }
__device__ inline float fsig(float x) { return __builtin_amdgcn_rcpf(1.f + __expf(-x)); }
__device__ inline float ftanh(float x) {
  float t = __expf(-2.f * fabsf(x));
  return copysignf((1.f - t) * __builtin_amdgcn_rcpf(1.f + t), x);
}

// bf16 weight mats, row-major [128][128]:
// 0: Wzf  1: Wzh  2: Wr  3: Whf  4: Whh  5: Ur
__global__ __launch_bounds__(256) void conv_weights(
    const float* __restrict__ Wz, const float* __restrict__ Wr,
    const float* __restrict__ Ur, const float* __restrict__ Wh,
    short* __restrict__ out)
{
  int i = blockIdx.x * 256 + threadIdx.x;
  if (i >= 6 * 16384) return;
  int mat = i >> 14, idx = i & 16383;
  int o = idx >> 7, c = idx & 127;
  float v = 0.f;
  switch (mat) {
    case 0: v = Wz[o * 256 + c];        break;
    case 1: v = Wz[o * 256 + 128 + c];  break;
    case 2: v = Wr[o * 128 + c];        break;
    case 3: v = Wh[o * 256 + c];        break;
    case 4: v = Wh[o * 256 + 128 + c];  break;
    case 5: v = Ur[o * 128 + c];        break;
  }
  out[i] = (short)f2bf(v);
}

__global__ __launch_bounds__(256) void conv_fmess(const float* __restrict__ src,
                                                  u16t* __restrict__ dst, size_t n8)
{
  size_t i = (size_t)blockIdx.x * 256 + threadIdx.x;
  if (i >= n8) return;
  const float4 a = *reinterpret_cast<const float4*>(src + i * 8);
  const float4 b = *reinterpret_cast<const float4*>(src + i * 8 + 4);
  uint4 o;
  o.x = ((u32t)f2bf(a.y) << 16) | f2bf(a.x);
  o.y = ((u32t)f2bf(a.w) << 16) | f2bf(a.z);
  o.z = ((u32t)f2bf(b.y) << 16) | f2bf(b.x);
  o.w = ((u32t)f2bf(b.w) << 16) | f2bf(b.z);
  *reinterpret_cast<uint4*>(dst + i * 8) = o;
}

// Detect whether bgraph arrived as int64 (odd 32-bit words all zero).
__global__ void detect64(const int* __restrict__ bg, int* __restrict__ flag) {
  int t = threadIdx.x;
  int v = bg[2 * t + 1];
  unsigned long long m = __ballot(v == 0);
  if (t == 0) *flag = (m == ~0ull) ? 1 : 0;
}

// MODE: 0 = first step (h=0: no gather), 1 = middle, 2 = last (fp32 out, no P)
// Combined state array C[e][c] = (P_bf16 << 16) | h_bf16.
template<int MODE>
__global__ __launch_bounds__(256, 3) void step_k(
    const float* __restrict__ fmess,      // fp32 fallback
    const u16t* __restrict__ fmb,         // bf16 fmess (preferred, may be null)
    const int* __restrict__ bg,
    const int* __restrict__ flag64,
    const u32t* __restrict__ Cin,
    const short* __restrict__ wbf,
    const float* __restrict__ bz, const float* __restrict__ urb, const float* __restrict__ bh,
    u32t* __restrict__ Cout,              // MODE 0/1
    float* __restrict__ houtf,            // MODE 2
    int E)
{
  __shared__ __align__(16) short s_fm[32][136];
  __shared__ __align__(16) short s_R1[32][136];
  __shared__ __align__(16) short s_sb[32][136];
  __shared__ __align__(16) short s_gb[32][136];
  __shared__ __align__(16) float s_sum[32][128];

  const int tid = threadIdx.x, wave = tid >> 6, lane = tid & 63;
  const int cl = lane & 15, kg = lane >> 4;
  const int base = blockIdx.x * 32;
  const int mrow = (wave & 1) * 16, ncol = (wave >> 1) * 64;

  // ---- phase 1: fmess tile -> LDS bf16 ----
  if (fmb) {
    #pragma unroll
    for (int it = 0; it < 2; ++it) {
      int idx = it * 256 + tid;           // 512 slots x 16B
      int r = idx >> 4, c = (idx & 15) * 8;
      uint4 v = {0u, 0u, 0u, 0u};
      int e = base + r;
      if (e < E) v = *reinterpret_cast<const uint4*>(fmb + (size_t)e * 128 + c);
      *reinterpret_cast<uint4*>(&s_fm[r][c]) = v;
    }
  } else {
    #pragma unroll
    for (int it = 0; it < 4; ++it) {
      int idx = it * 256 + tid;           // 1024 float4 slots
      int r = idx >> 5, c = (idx & 31) << 2;
      float4 v = {0.f, 0.f, 0.f, 0.f};
      int e = base + r;
      if (e < E) v = *reinterpret_cast<const float4*>(fmess + (size_t)e * 128 + c);
      s_fm[r][c]     = (short)f2bf(v.x);
      s_fm[r][c + 1] = (short)f2bf(v.y);
      s_fm[r][c + 2] = (short)f2bf(v.z);
      s_fm[r][c + 3] = (short)f2bf(v.w);
    }
  }
  __syncthreads();

  // ---- phase 2: fmess projections ----
  bf16x8 af[4];
  #pragma unroll
  for (int ks = 0; ks < 4; ++ks)
    af[ks] = *reinterpret_cast<const bf16x8*>(&s_fm[mrow + cl][ks * 32 + kg * 8]);

  const short* Wzf = wbf;
  const short* Wzh = wbf + 1 * 16384;
  const short* Wr  = wbf + 2 * 16384;
  const short* Whf = wbf + 3 * 16384;
  const short* Whh = wbf + 4 * 16384;
  const short* Ur  = wbf + 5 * 16384;

  f32x4 zacc[4], hacc[4];
  #pragma unroll
  for (int nt = 0; nt < 4; ++nt) { zacc[nt] = (f32x4){0,0,0,0}; hacc[nt] = (f32x4){0,0,0,0}; }
  #pragma unroll
  for (int ks = 0; ks < 4; ++ks) {
    #pragma unroll
    for (int nt = 0; nt < 4; ++nt) {
      int n = ncol + nt * 16 + cl;
      bf16x8 b1 = *reinterpret_cast<const bf16x8*>(Wzf + (size_t)n * 128 + ks * 32 + kg * 8);
      zacc[nt] = __builtin_amdgcn_mfma_f32_16x16x32_bf16(af[ks], b1, zacc[nt], 0, 0, 0);
      bf16x8 b2 = *reinterpret_cast<const bf16x8*>(Whf + (size_t)n * 128 + ks * 32 + kg * 8);
      hacc[nt] = __builtin_amdgcn_mfma_f32_16x16x32_bf16(af[ks], b2, hacc[nt], 0, 0, 0);
    }
  }

  f32x4 accz[4], acch[4];
  #pragma unroll
  for (int nt = 0; nt < 4; ++nt) { accz[nt] = (f32x4){0,0,0,0}; acch[nt] = (f32x4){0,0,0,0}; }

  if (MODE != 0) {
    // R1 = fmess @ Wr^T + urb -> LDS bf16
    f32x4 racc[4];
    #pragma unroll
    for (int nt = 0; nt < 4; ++nt) racc[nt] = (f32x4){0,0,0,0};
    #pragma unroll
    for (int ks = 0; ks < 4; ++ks) {
      #pragma unroll
      for (int nt = 0; nt < 4; ++nt) {
        bf16x8 b = *reinterpret_cast<const bf16x8*>(Wr + (size_t)(ncol + nt * 16 + cl) * 128 + ks * 32 + kg * 8);
        racc[nt] = __builtin_amdgcn_mfma_f32_16x16x32_bf16(af[ks], b, racc[nt], 0, 0, 0);
      }
    }
    #pragma unroll
    for (int nt = 0; nt < 4; ++nt) {
      int n = ncol + nt * 16 + cl;
      float bias = urb[n];
      #pragma unroll
      for (int r = 0; r < 4; ++r)
        s_R1[mrow + kg * 4 + r][n] = (short)f2bf(racc[nt][r] + bias);
    }
    __syncthreads();

    // ---- phase 3: gather combined h|P rows ----
    const int f64 = *flag64;
    const int l5 = lane & 31, half = lane >> 5;
    // coalesced index preload: lane (rL*8 + k) holds bg[base+wave*8+rL][k]
    int idx_all = 0;
    {
      int er = base + wave * 8 + (lane >> 3);
      if (er < E) {
        size_t p = (size_t)er * 8 + (lane & 7);
        idx_all = f64 ? bg[p * 2] : bg[p];
      }
    }
    #pragma unroll 2
    for (int rr = 0; rr < 8; ++rr) {
      int row = wave * 8 + rr;
      int e = base + row;
      float sh[4] = {0.f, 0.f, 0.f, 0.f};
      float g[4]  = {0.f, 0.f, 0.f, 0.f};
      uint2 r1p = *reinterpret_cast<const uint2*>(&s_R1[row][l5 * 4]);
      float r1[4] = { ubits(r1p.x << 16), ubits(r1p.x & 0xffff0000u),
                      ubits(r1p.y << 16), ubits(r1p.y & 0xffff0000u) };
      if (e < E) {
        #pragma unroll
        for (int t = 0; t < 4; ++t) {
          int idx = __shfl(idx_all, rr * 8 + t * 2 + half);
          uint4 v = *reinterpret_cast<const uint4*>(Cin + (size_t)idx * 128 + l5 * 4);
          u32t w[4] = {v.x, v.y, v.z, v.w};
          #pragma unroll
          for (int j = 0; j < 4; ++j) {
            float hv = ubits(w[j] << 16);
            float pv = ubits(w[j] & 0xffff0000u);
            sh[j] += hv;
            g[j]  += fsig(r1[j] + pv) * hv;
          }
        }
      }
      #pragma unroll
      for (int j = 0; j < 4; ++j) {
        sh[j] += __shfl_xor(sh[j], 32);
        g[j]  += __shfl_xor(g[j], 32);
      }
      if (half == 0) {
        float4 sv = {sh[0], sh[1], sh[2], sh[3]};
        *reinterpret_cast<float4*>(&s_sum[row][l5 * 4]) = sv;
        uint2 sp, gp;
        sp.x = ((u32t)f2bf(sh[1]) << 16) | f2bf(sh[0]);
        sp.y = ((u32t)f2bf(sh[3]) << 16) | f2bf(sh[2]);
        gp.x = ((u32t)f2bf(g[1]) << 16) | f2bf(g[0]);
        gp.y = ((u32t)f2bf(g[3]) << 16) | f2bf(g[2]);
        *reinterpret_cast<uint2*>(&s_sb[row][l5 * 4]) = sp;
        *reinterpret_cast<uint2*>(&s_gb[row][l5 * 4]) = gp;
      }
    }
    __syncthreads();

    // ---- phase 4: z/h hidden-state GEMMs ----
    bf16x8 az[4], ag[4];
    #pragma unroll
    for (int ks = 0; ks < 4; ++ks) {
      az[ks] = *reinterpret_cast<const bf16x8*>(&s_sb[mrow + cl][ks * 32 + kg * 8]);
      ag[ks] = *reinterpret_cast<const bf16x8*>(&s_gb[mrow + cl][ks * 32 + kg * 8]);
    }
    #pragma unroll
    for (int ks = 0; ks < 4; ++ks) {
      #pragma unroll
      for (int nt = 0; nt < 4; ++nt) {
        int n = ncol + nt * 16 + cl;
        bf16x8 b1 = *reinterpret_cast<const bf16x8*>(Wzh + (size_t)n * 128 + ks * 32 + kg * 8);
        accz[nt] = __builtin_amdgcn_mfma_f32_16x16x32_bf16(az[ks], b1, accz[nt], 0, 0, 0);
        bf16x8 b2 = *reinterpret_cast<const bf16x8*>(Whh + (size_t)n * 128 + ks * 32 + kg * 8);
        acch[nt] = __builtin_amdgcn_mfma_f32_16x16x32_bf16(ag[ks], b2, acch[nt], 0, 0, 0);
      }
    }
  }

  // ---- phase 5: GRU epilogue ----
  float nh_sv[4][4];
  #pragma unroll
  for (int nt = 0; nt < 4; ++nt) {
    int n = ncol + nt * 16 + cl;
    float bzv = bz[n], bhv = bh[n];
    #pragma unroll
    for (int r = 0; r < 4; ++r) {
      int rowt = mrow + kg * 4 + r;
      int e = base + rowt;
      float z   = fsig(zacc[nt][r] + accz[nt][r] + bzv);
      float pre = ftanh(hacc[nt][r] + acch[nt][r] + bhv);
      float sh  = (MODE == 0) ? 0.f : s_sum[rowt][n];
      float nh  = (1.f - z) * sh + z * pre;
      if (e == 0) nh = 0.f;
      if (MODE == 2) {
        if (e < E) houtf[(size_t)e * 128 + n] = nh;
      } else {
        nh_sv[nt][r] = nh;
      }
    }
  }

  // ---- phase 6: P_next = h_next @ Ur^T, store packed (P<<16)|h ----
  if (MODE != 2) {
    __syncthreads();   // all phase-4 frag reads / phase-5 s_sum reads done
    #pragma unroll
    for (int nt = 0; nt < 4; ++nt) {
      int n = ncol + nt * 16 + cl;
      #pragma unroll
      for (int r = 0; r < 4; ++r)
        s_sb[mrow + kg * 4 + r][n] = (short)f2bf(nh_sv[nt][r]);
    }
    __syncthreads();
    bf16x8 ah[4];
    #pragma unroll
    for (int ks = 0; ks < 4; ++ks)
      ah[ks] = *reinterpret_cast<const bf16x8*>(&s_sb[mrow + cl][ks * 32 + kg * 8]);
    f32x4 pacc[4];
    #pragma unroll
    for (int nt = 0; nt < 4; ++nt) pacc[nt] = (f32x4){0,0,0,0};
    #pragma unroll
    for (int ks = 0; ks < 4; ++ks) {
      #pragma unroll
      for (int nt = 0; nt < 4; ++nt) {
        bf16x8 b = *reinterpret_cast<const bf16x8*>(Ur + (size_t)(ncol + nt * 16 + cl) * 128 + ks * 32 + kg * 8);
        pacc[nt] = __builtin_amdgcn_mfma_f32_16x16x32_bf16(ah[ks], b, pacc[nt], 0, 0, 0);
      }
    }
    #pragma unroll
    for (int nt = 0; nt < 4; ++nt) {
      int n = ncol + nt * 16 + cl;
      #pragma unroll
      for (int r = 0; r < 4; ++r) {
        int e = base + mrow + kg * 4 + r;
        if (e < E) {
          u32t pk = ((u32t)f2bf(pacc[nt][r]) << 16) | f2bf(nh_sv[nt][r]);
          Cout[(size_t)e * 128 + n] = pk;
        }
      }
    }
  }
}

extern "C" void kernel_launch(void* const* d_in, const int* in_sizes, int n_in,
                              void* d_out, int out_size, void* d_ws, size_t ws_size,
                              hipStream_t stream) {
  const float* fmess = (const float*)d_in[0];
  const int*   bg    = (const int*)d_in[1];
  const float* Wz    = (const float*)d_in[2];
  const float* bz    = (const float*)d_in[3];
  const float* Wrw   = (const float*)d_in[4];
  const float* Urw   = (const float*)d_in[5];
  const float* urb   = (const float*)d_in[6];
  const float* Wh    = (const float*)d_in[7];
  const float* bh    = (const float*)d_in[8];
  float* out = (float*)d_out;

  const int E = in_sizes[0] / 128;
  const size_t EH = (size_t)E * 128;
  const size_t wshorts = 6 * 16384;

  u32t* CB = (u32t*)d_out;          // d_out doubles as combined scratch until last step
  u32t* CA = (u32t*)d_ws;

  // ws layout: CA (EH u32) | [fmb (EH u16)] | wbf | flag
  u16t* fmb = nullptr;
  short* wbf;
  size_t need_full = EH * 4 + EH * 2 + wshorts * 2 + 64;
  if (ws_size >= need_full) {
    fmb = (u16t*)(CA + EH);
    wbf = (short*)(fmb + EH);
  } else {
    wbf = (short*)(CA + EH);
  }
  int* flag = (int*)(wbf + wshorts);

  conv_weights<<<384, 256, 0, stream>>>(Wz, Wrw, Urw, Wh, wbf);
  detect64<<<1, 64, 0, stream>>>(bg, flag);
  if (fmb) {
    size_t n8 = EH / 8;
    conv_fmess<<<(int)((n8 + 255) / 256), 256, 0, stream>>>(fmess, fmb, n8);
  }

  const int grid = (E + 31) / 32;
  // s0: -> CB ; s1: CB->CA ; s2: CA->CB ; s3: CB->CA ; s4: CA -> out(fp32)
  step_k<0><<<grid, 256, 0, stream>>>(fmess, fmb, bg, flag, nullptr, wbf, bz, urb, bh, CB, nullptr, E);
  step_k<1><<<grid, 256, 0, stream>>>(fmess, fmb, bg, flag, CB, wbf, bz, urb, bh, CA, nullptr, E);
  step_k<1><<<grid, 256, 0, stream>>>(fmess, fmb, bg, flag, CA, wbf, bz, urb, bh, CB, nullptr, E);
  step_k<1><<<grid, 256, 0, stream>>>(fmess, fmb, bg, flag, CB, wbf, bz, urb, bh, CA, nullptr, E);
  step_k<2><<<grid, 256, 0, stream>>>(fmess, fmb, bg, flag, CA, wbf, bz, urb, bh, nullptr, out, E);
}